// Round 1
// 207.360 us; speedup vs baseline: 1.0303x; 1.0303x over previous
//
#include <hip/hip_runtime.h>

#define NP 250000   // P: permutations
#define NN 100000   // N: nodes
#define NE 400000   // E: edges
#define LL 16
#define DD 16
#define MM (NP * LL)        // 4,000,000
#define NTILES (NP / 16)    // 15625 exact

typedef __bf16 bf16x8 __attribute__((ext_vector_type(8)));
typedef float f32x4 __attribute__((ext_vector_type(4)));

__device__ __forceinline__ float4 fma4(float a, float4 b, float4 c) {
    float4 r;
    r.x = fmaf(a, b.x, c.x);
    r.y = fmaf(a, b.y, c.y);
    r.z = fmaf(a, b.z, c.z);
    r.w = fmaf(a, b.w, c.w);
    return r;
}

// K-mapping for mfma_16x16x32_bf16, kb (0..7), lane (quad=lane>>4, c=lane&15):
//   d = 8*(quad&1) + j,  l = 8*(quad>>1) + kb
// wfrag[kb*512 + lane*8 + j] = weights[d][c][l]  (B-fragment order)
// Also: nfeat->bf16 table, bond->bf16, zero out, be2 packed bond indices,
// and (fused-gate path) fd[n,c] = (relu(degs[n]*W0+b0) @ W1 + b1)[c].
__global__ __launch_bounds__(256) void init_kernel(
    const float* __restrict__ w,          // [16,16,16] (d,c,l)
    const float* __restrict__ nfeat,      // [N,16]
    const float* __restrict__ bond_emb,   // [4,16]
    const int* __restrict__ e_col,        // [M]
    const int* __restrict__ efeat_idx,    // [E]
    const float* __restrict__ degs,       // [N]
    const float* __restrict__ W0,         // [1,32]
    const float* __restrict__ b0,         // [32]
    const float* __restrict__ W1,         // [32,16]
    const float* __restrict__ b1,         // [16]
    __bf16* __restrict__ wfrag,           // [8*64*8]
    __bf16* __restrict__ nfeat_bf,        // [N,16]
    __bf16* __restrict__ bond_bf,         // [4,16]
    unsigned char* __restrict__ be2,      // [M/4]
    float* __restrict__ fd,               // [N,16] or nullptr
    float* __restrict__ out)              // [N,16] -> zeroed
{
    int t = blockIdx.x * 256 + threadIdx.x;
    if (t < 4096) {
        int kb = t >> 9;
        int lane = (t >> 3) & 63;
        int j = t & 7;
        int quad = lane >> 4, c = lane & 15;
        int d = ((quad & 1) << 3) + j;
        int l = ((quad >> 1) << 3) + kb;
        wfrag[t] = (__bf16)w[d * 256 + c * 16 + l];
    }
    if (t < NN * DD) {
        nfeat_bf[t] = (__bf16)nfeat[t];
        out[t] = 0.f;
    }
    if (t < 64) bond_bf[t] = (__bf16)bond_emb[t];
    if (t < MM / 4) {
        int4 ec = *(const int4*)(e_col + t * 4);
        unsigned int c0 = (unsigned int)efeat_idx[ec.x] & 3u;
        unsigned int c1 = (unsigned int)efeat_idx[ec.y] & 3u;
        unsigned int c2 = (unsigned int)efeat_idx[ec.z] & 3u;
        unsigned int c3 = (unsigned int)efeat_idx[ec.w] & 3u;
        be2[t] = (unsigned char)(c0 | (c1 << 2) | (c2 << 4) | (c3 << 6));
    }
    if (fd != nullptr && t < NN) {
        float dg = degs[t];
        float4 a0 = ((const float4*)b1)[0];
        float4 a1 = ((const float4*)b1)[1];
        float4 a2 = ((const float4*)b1)[2];
        float4 a3 = ((const float4*)b1)[3];
#pragma unroll
        for (int j2 = 0; j2 < 32; ++j2) {
            float h = fmaxf(fmaf(dg, W0[j2], b0[j2]), 0.f);
            const float4* w1r = (const float4*)(W1 + j2 * 16);
            a0 = fma4(h, w1r[0], a0);
            a1 = fma4(h, w1r[1], a1);
            a2 = fma4(h, w1r[2], a2);
            a3 = fma4(h, w1r[3], a3);
        }
        float4* o = (float4*)(fd + (size_t)t * DD);
        o[0] = a0; o[1] = a1; o[2] = a2; o[3] = a3;
    }
}

// 256-thread blocks, FOUR independent 1-wave tiles per block (no LDS, no
// __syncthreads): lifts the 1-wave-workgroup occupancy cap (~16 wg/CU = 45%)
// to the full 32 waves/CU so the dependent load chain (n_col stream ->
// nfeat_bf L2 gather -> A-frag VALU -> MFMA -> atomic) is hidden by TLP.
// A[m=col][k=quad*8+j]; lane's rows are the 8 CONSECUTIVE
// l = 8*(quad>>1)..+7 of perm pbase+col.
// C/D: col=lane&15 (channel), row=quad*4+reg (perm-in-tile).
__global__ __launch_bounds__(256) void perm_kernel(
    const __bf16* __restrict__ nfeat_bf,   // [N,16] bf16
    const int* __restrict__ n_col,         // [M]
    const float* __restrict__ n_val,       // [M]
    const float* __restrict__ e_val,       // [M]
    const unsigned char* __restrict__ be2, // [M/4] packed bond indices
    const int* __restrict__ p_row,         // [P]
    const float* __restrict__ p_val,       // [P]
    const __bf16* __restrict__ wfrag,      // [8*64*8]
    const float* __restrict__ bias,        // [16]
    const __bf16* __restrict__ bond_bf,    // [4,16] bf16
    const float* __restrict__ fd,          // [N,16] gate table, or nullptr
    float* __restrict__ out)               // [N,16] zero-initialized
{
    const int wid = threadIdx.x >> 6;      // wave in block, 0..3
    const int lane = threadIdx.x & 63;     // 0..63
    const int tile = blockIdx.x * 4 + wid;
    if (tile >= NTILES) return;
    const int quad = lane >> 4;
    const int col = lane & 15;
    const int half = quad & 1;    // d-half this lane holds
    const int lhalf = quad >> 1;  // l-half this lane covers

    const int pbase = tile * 16;
    const int mbase = (pbase + col) * LL + lhalf * 8;

    // issue ALL independent loads up front
    int4   nca = *(const int4*)(n_col + mbase);
    int4   ncb = *(const int4*)(n_col + mbase + 4);
    float4 nva = *(const float4*)(n_val + mbase);
    float4 nvb = *(const float4*)(n_val + mbase + 4);
    float4 eva = *(const float4*)(e_val + mbase);
    float4 evb = *(const float4*)(e_val + mbase + 4);
    unsigned int be16 = *(const unsigned short*)(be2 + (mbase >> 2));
    int4   pr  = *(const int4*)(p_row + pbase + quad * 4);
    float4 pvv = *(const float4*)(p_val + pbase + quad * 4);

    // gate-table gathers for the epilogue: issued here so they ride under
    // the MFMA phase (fd is L2/L3-resident, 6.4 MB)
    int   prs[4] = {pr.x, pr.y, pr.z, pr.w};
    float gv[4] = {1.f, 1.f, 1.f, 1.f};
    if (fd != nullptr) {
#pragma unroll
        for (int r = 0; r < 4; ++r)
            gv[r] = fd[(size_t)prs[r] * DD + col];
    }

    // weight B-fragments + bond rows + bias (L2-hot, 8 KB shared by all blocks)
    bf16x8 wf[8];
#pragma unroll
    for (int kb = 0; kb < 8; ++kb)
        wf[kb] = *(const bf16x8*)(wfrag + (kb * 64 + lane) * 8);
    const bf16x8 bq0 = *(const bf16x8*)(bond_bf + 0 * 16 + half * 8);
    const bf16x8 bq1 = *(const bf16x8*)(bond_bf + 1 * 16 + half * 8);
    const bf16x8 bq2 = *(const bf16x8*)(bond_bf + 2 * 16 + half * 8);
    const bf16x8 bq3 = *(const bf16x8*)(bond_bf + 3 * 16 + half * 8);
    const float bias_c = bias[col];

    int   ncs[8] = {nca.x, nca.y, nca.z, nca.w, ncb.x, ncb.y, ncb.z, ncb.w};
    float nvs[8] = {nva.x, nva.y, nva.z, nva.w, nvb.x, nvb.y, nvb.z, nvb.w};
    float evs[8] = {eva.x, eva.y, eva.z, eva.w, evb.x, evb.y, evb.z, evb.w};

    // independent row gathers, all issued before first MFMA
    bf16x8 nfr[8];
#pragma unroll
    for (int kb = 0; kb < 8; ++kb)
        nfr[kb] = *(const bf16x8*)(nfeat_bf + ncs[kb] * DD + half * 8);

    f32x4 acc = {0.f, 0.f, 0.f, 0.f};
#pragma unroll
    for (int kb = 0; kb < 8; ++kb) {
        unsigned int b = (be16 >> (2 * kb)) & 3u;
        bf16x8 blo = (b & 1) ? bq1 : bq0;
        bf16x8 bhi = (b & 1) ? bq3 : bq2;
        bf16x8 bsel = (b & 2) ? bhi : blo;
        float nv = nvs[kb], ev = evs[kb];
        bf16x8 af;
#pragma unroll
        for (int j = 0; j < 8; ++j)
            af[j] = (__bf16)fmaf(nv, (float)nfr[kb][j], ev * (float)bsel[j]);
        acc = __builtin_amdgcn_mfma_f32_16x16x32_bf16(af, wf[kb], acc, 0, 0, 0);
    }

    // epilogue: lane commits channel `col` of its quad's 4 perms,
    // pre-scaled by p_val and (fused path) the degree gate
    float pvs[4] = {pvv.x, pvv.y, pvv.z, pvv.w};
#pragma unroll
    for (int r = 0; r < 4; ++r) {
        float v = fmaxf(acc[r] + bias_c, 0.f) * pvs[r] * gv[r];
        unsafeAtomicAdd(out + (size_t)prs[r] * DD + col, v);
    }
}

// fallback only (workspace too small for fd table)
__global__ __launch_bounds__(256) void gate_kernel(
    const float* __restrict__ degs,  // [N]
    const float* __restrict__ W0,    // [1,32]
    const float* __restrict__ b0,    // [32]
    const float* __restrict__ W1,    // [32,16]
    const float* __restrict__ b1,    // [16]
    float* __restrict__ out)         // [N,16] in-place multiply
{
    int n = blockIdx.x * 256 + threadIdx.x;
    if (n >= NN) return;
    float dg = degs[n];
    float4 a0 = ((const float4*)b1)[0];
    float4 a1 = ((const float4*)b1)[1];
    float4 a2 = ((const float4*)b1)[2];
    float4 a3 = ((const float4*)b1)[3];
#pragma unroll
    for (int j = 0; j < 32; ++j) {
        float h = fmaxf(fmaf(dg, W0[j], b0[j]), 0.f);
        const float4* w1r = (const float4*)(W1 + j * 16);
        a0 = fma4(h, w1r[0], a0);
        a1 = fma4(h, w1r[1], a1);
        a2 = fma4(h, w1r[2], a2);
        a3 = fma4(h, w1r[3], a3);
    }
    float4* o = (float4*)(out + (size_t)n * DD);
    float4 v0 = o[0], v1 = o[1], v2 = o[2], v3 = o[3];
    v0.x *= a0.x; v0.y *= a0.y; v0.z *= a0.z; v0.w *= a0.w;
    v1.x *= a1.x; v1.y *= a1.y; v1.z *= a1.z; v1.w *= a1.w;
    v2.x *= a2.x; v2.y *= a2.y; v2.z *= a2.z; v2.w *= a2.w;
    v3.x *= a3.x; v3.y *= a3.y; v3.z *= a3.z; v3.w *= a3.w;
    o[0] = v0; o[1] = v1; o[2] = v2; o[3] = v3;
}

extern "C" void kernel_launch(void* const* d_in, const int* in_sizes, int n_in,
                              void* d_out, int out_size, void* d_ws, size_t ws_size,
                              hipStream_t stream) {
    const float* nfeat     = (const float*)d_in[0];
    const int*   efeat_idx = (const int*)d_in[1];
    // d_in[2] n_row = arange(M), unused
    const int*   n_col     = (const int*)d_in[3];
    const float* n_val     = (const float*)d_in[4];
    // d_in[5] e_row = arange(M), unused
    const int*   e_col     = (const int*)d_in[6];
    const float* e_val     = (const float*)d_in[7];
    const int*   p_row     = (const int*)d_in[8];
    // d_in[9] p_col = arange(P), unused
    const float* p_val     = (const float*)d_in[10];
    const float* degs      = (const float*)d_in[11];
    const float* weights   = (const float*)d_in[12];
    const float* bias      = (const float*)d_in[13];
    const float* W0        = (const float*)d_in[14];
    const float* b0        = (const float*)d_in[15];
    const float* W1        = (const float*)d_in[16];
    const float* b1        = (const float*)d_in[17];
    const float* bond_emb  = (const float*)d_in[18];

    float* out = (float*)d_out;

    // ws layout (16B-aligned blocks):
    //   wfrag 8KB | nfeat_bf 3.2MB | bond 128B | be2 1MB | fd 6.4MB (if it fits)
    char* wsb = (char*)d_ws;
    __bf16*        wfrag    = (__bf16*)wsb;                                // 8192 B
    __bf16*        nfeat_bf = (__bf16*)(wsb + 8192);                       // 3,200,000 B
    __bf16*        bond_bf  = (__bf16*)(wsb + 8192 + 3200000);             // 128 B
    unsigned char* be2      = (unsigned char*)(wsb + 8192 + 3200000 + 128);// 1,000,000 B
    const size_t base_need  = 8192 + 3200000 + 128 + 1000000;              // 4,208,320
    const bool   fuse_gate  = ws_size >= base_need + (size_t)NN * DD * 4;
    float*         fd       = fuse_gate ? (float*)(wsb + base_need) : nullptr;

    // grid must cover max(NN*DD, MM/4) = 1.6M threads
    init_kernel<<<(NN * DD + 255) / 256, 256, 0, stream>>>(
        weights, nfeat, bond_emb, e_col, efeat_idx,
        degs, W0, b0, W1, b1,
        wfrag, nfeat_bf, bond_bf, be2, fd, out);

    // 4 independent 1-wave tiles per 256-thread block
    perm_kernel<<<(NTILES + 3) / 4, 256, 0, stream>>>(
        nfeat_bf, n_col, n_val, e_val, be2, p_row, p_val,
        wfrag, bias, bond_bf, fd, out);

    if (!fuse_gate)
        gate_kernel<<<(NN + 255) / 256, 256, 0, stream>>>(degs, W0, b0, W1, b1, out);
}

// Round 2
// 204.492 us; speedup vs baseline: 1.0447x; 1.0140x over previous
//
#include <hip/hip_runtime.h>

#define NP 250000   // P: permutations
#define NN 100000   // N: nodes
#define NE 400000   // E: edges
#define LL 16
#define DD 16
#define MM (NP * LL)        // 4,000,000
#define NTILES (NP / 16)    // 15625 exact
#define PERM_BLOCKS 512
#define GWAVES (PERM_BLOCKS * 4)   // 2048 waves, ~7.6 tiles each

typedef __bf16 bf16x8 __attribute__((ext_vector_type(8)));
typedef float  f32x4  __attribute__((ext_vector_type(4)));
typedef int    i32x4  __attribute__((ext_vector_type(4)));

__device__ __forceinline__ float4 fma4(float a, float4 b, float4 c) {
    float4 r;
    r.x = fmaf(a, b.x, c.x);
    r.y = fmaf(a, b.y, c.y);
    r.z = fmaf(a, b.z, c.z);
    r.w = fmaf(a, b.w, c.w);
    return r;
}

// K-mapping for mfma_16x16x32_bf16, kb (0..7), lane (quad=lane>>4, c=lane&15):
//   d = 8*(quad&1) + j,  l = 8*(quad>>1) + kb
// wfrag[kb*512 + lane*8 + j] = weights[d][c][l]  (B-fragment order)
__global__ __launch_bounds__(256) void init_kernel(
    const float* __restrict__ w,          // [16,16,16] (d,c,l)
    const float* __restrict__ nfeat,      // [N,16]
    const float* __restrict__ bond_emb,   // [4,16]
    const int* __restrict__ e_col,        // [M]
    const int* __restrict__ efeat_idx,    // [E]
    const float* __restrict__ degs,       // [N]
    const float* __restrict__ W0,         // [1,32]
    const float* __restrict__ b0,         // [32]
    const float* __restrict__ W1,         // [32,16]
    const float* __restrict__ b1,         // [16]
    __bf16* __restrict__ wfrag,           // [8*64*8]
    __bf16* __restrict__ nfeat_bf,        // [N,16]
    __bf16* __restrict__ bond_bf,         // [4,16]
    unsigned char* __restrict__ be2,      // [M/4]
    float* __restrict__ fd,               // [N,16] or nullptr
    float* __restrict__ out)              // [N,16] -> zeroed
{
    int t = blockIdx.x * 256 + threadIdx.x;
    if (t < 4096) {
        int kb = t >> 9;
        int lane = (t >> 3) & 63;
        int j = t & 7;
        int quad = lane >> 4, c = lane & 15;
        int d = ((quad & 1) << 3) + j;
        int l = ((quad >> 1) << 3) + kb;
        wfrag[t] = (__bf16)w[d * 256 + c * 16 + l];
    }
    if (t < NN * DD) {
        nfeat_bf[t] = (__bf16)nfeat[t];
        out[t] = 0.f;
    }
    if (t < 64) bond_bf[t] = (__bf16)bond_emb[t];
    if (t < MM / 4) {
        int4 ec = *(const int4*)(e_col + t * 4);
        unsigned int c0 = (unsigned int)efeat_idx[ec.x] & 3u;
        unsigned int c1 = (unsigned int)efeat_idx[ec.y] & 3u;
        unsigned int c2 = (unsigned int)efeat_idx[ec.z] & 3u;
        unsigned int c3 = (unsigned int)efeat_idx[ec.w] & 3u;
        be2[t] = (unsigned char)(c0 | (c1 << 2) | (c2 << 4) | (c3 << 6));
    }
    if (fd != nullptr && t < NN) {
        float dg = degs[t];
        float4 a0 = ((const float4*)b1)[0];
        float4 a1 = ((const float4*)b1)[1];
        float4 a2 = ((const float4*)b1)[2];
        float4 a3 = ((const float4*)b1)[3];
#pragma unroll
        for (int j2 = 0; j2 < 32; ++j2) {
            float h = fmaxf(fmaf(dg, W0[j2], b0[j2]), 0.f);
            const float4* w1r = (const float4*)(W1 + j2 * 16);
            a0 = fma4(h, w1r[0], a0);
            a1 = fma4(h, w1r[1], a1);
            a2 = fma4(h, w1r[2], a2);
            a3 = fma4(h, w1r[3], a3);
        }
        float4* o = (float4*)(fd + (size_t)t * DD);
        o[0] = a0; o[1] = a1; o[2] = a2; o[3] = a3;
    }
}

// ---- pipelined perm kernel -------------------------------------------------
// Each wave owns ~7.6 tiles (grid-stride GWAVES). Depth-3 pipeline:
//   streams(t+2) in flight (HBM, ~1.5 compute phases to land)
//   gathers(t+1) in flight (L2, issued mid-compute of t)
//   compute(t)  (A-build + 8 MFMA + fire-and-forget atomics)
// Early group (n_col, p_row) is needed at gather-issue time; late group
// (n_val/e_val/p_val/be2) only at compute time. Named ping-pong structs keep
// all indexing compile-time constant (no scratch).

struct Early { i32x4 nca, ncb, pr; };
struct Late  { f32x4 nva, nvb, eva, evb, pv; unsigned int be16; };
struct Gath  { bf16x8 nfr[8]; float gv[4]; int prs[4]; };

__device__ __forceinline__ void load_early(Early& e, int tile, int col, int lhalf, int quad,
        const int* __restrict__ n_col, const int* __restrict__ p_row) {
    const int pbase = tile * 16;
    const int mbase = (pbase + col) * LL + lhalf * 8;
    e.nca = __builtin_nontemporal_load((const i32x4*)(n_col + mbase));
    e.ncb = __builtin_nontemporal_load((const i32x4*)(n_col + mbase + 4));
    e.pr  = __builtin_nontemporal_load((const i32x4*)(p_row + pbase + quad * 4));
}

__device__ __forceinline__ void load_late(Late& lt, int tile, int col, int lhalf, int quad,
        const float* __restrict__ n_val, const float* __restrict__ e_val,
        const unsigned char* __restrict__ be2, const float* __restrict__ p_val) {
    const int pbase = tile * 16;
    const int mbase = (pbase + col) * LL + lhalf * 8;
    lt.nva = __builtin_nontemporal_load((const f32x4*)(n_val + mbase));
    lt.nvb = __builtin_nontemporal_load((const f32x4*)(n_val + mbase + 4));
    lt.eva = __builtin_nontemporal_load((const f32x4*)(e_val + mbase));
    lt.evb = __builtin_nontemporal_load((const f32x4*)(e_val + mbase + 4));
    lt.pv  = __builtin_nontemporal_load((const f32x4*)(p_val + pbase + quad * 4));
    lt.be16 = (unsigned int)__builtin_nontemporal_load(
                  (const unsigned short*)(be2 + (mbase >> 2)));
}

__device__ __forceinline__ void issue_gathers(Gath& g, const Early& e,
        const __bf16* __restrict__ nfeat_bf, const float* __restrict__ fd,
        int half, int col) {
    int ncs[8] = {e.nca[0], e.nca[1], e.nca[2], e.nca[3],
                  e.ncb[0], e.ncb[1], e.ncb[2], e.ncb[3]};
#pragma unroll
    for (int kb = 0; kb < 8; ++kb)
        g.nfr[kb] = *(const bf16x8*)(nfeat_bf + (size_t)ncs[kb] * DD + half * 8);
#pragma unroll
    for (int r = 0; r < 4; ++r) {
        g.prs[r] = e.pr[r];
        g.gv[r] = fd ? fd[(size_t)e.pr[r] * DD + col] : 1.f;
    }
}

#define KSTEP(G, KB, NV, EV, J) do { \
    unsigned int b = (be >> (2 * (KB))) & 3u; \
    bf16x8 blo = (b & 1) ? bq1 : bq0; \
    bf16x8 bhi = (b & 1) ? bq3 : bq2; \
    bf16x8 bsel = (b & 2) ? bhi : blo; \
    float nv = (NV)[J], ev = (EV)[J]; \
    bf16x8 af; \
    _Pragma("unroll") \
    for (int j = 0; j < 8; ++j) \
        af[j] = (__bf16)fmaf(nv, (float)G.nfr[KB][j], ev * (float)bsel[j]); \
    acc = __builtin_amdgcn_mfma_f32_16x16x32_bf16(af, wf[KB], acc, 0, 0, 0); \
} while (0)

#define STEP(C, N) { \
    f32x4 acc = {0.f, 0.f, 0.f, 0.f}; \
    const unsigned int be = lat##C.be16; \
    KSTEP(g##C, 0, lat##C.nva, lat##C.eva, 0); \
    KSTEP(g##C, 1, lat##C.nva, lat##C.eva, 1); \
    KSTEP(g##C, 2, lat##C.nva, lat##C.eva, 2); \
    KSTEP(g##C, 3, lat##C.nva, lat##C.eva, 3); \
    if (tn < NTILES) issue_gathers(g##N, ear##N, nfeat_bf, fd, half, col); \
    if (tf < NTILES) load_early(ear##C, tf, col, lhalf, quad, n_col, p_row); \
    KSTEP(g##C, 4, lat##C.nvb, lat##C.evb, 0); \
    KSTEP(g##C, 5, lat##C.nvb, lat##C.evb, 1); \
    KSTEP(g##C, 6, lat##C.nvb, lat##C.evb, 2); \
    KSTEP(g##C, 7, lat##C.nvb, lat##C.evb, 3); \
    _Pragma("unroll") \
    for (int r = 0; r < 4; ++r) { \
        float v = fmaxf(acc[r] + bias_c, 0.f) * lat##C.pv[r] * g##C.gv[r]; \
        unsafeAtomicAdd(out + (size_t)g##C.prs[r] * DD + col, v); \
    } \
    if (tf < NTILES) load_late(lat##C, tf, col, lhalf, quad, n_val, e_val, be2, p_val); \
    if (tn >= NTILES) goto tail_done; \
    tn = tf; tf += GWAVES; \
}

__global__ __launch_bounds__(256) void perm_kernel(
    const __bf16* __restrict__ nfeat_bf,   // [N,16] bf16
    const int* __restrict__ n_col,         // [M]
    const float* __restrict__ n_val,       // [M]
    const float* __restrict__ e_val,       // [M]
    const unsigned char* __restrict__ be2, // [M/4] packed bond indices
    const int* __restrict__ p_row,         // [P]
    const float* __restrict__ p_val,       // [P]
    const __bf16* __restrict__ wfrag,      // [8*64*8]
    const float* __restrict__ bias,        // [16]
    const __bf16* __restrict__ bond_bf,    // [4,16] bf16
    const float* __restrict__ fd,          // [N,16] gate table, or nullptr
    float* __restrict__ out)               // [N,16] zero-initialized
{
    const int wid  = threadIdx.x >> 6;
    const int lane = threadIdx.x & 63;
    const int gw   = blockIdx.x * 4 + wid;   // 0..GWAVES-1
    const int quad = lane >> 4;
    const int col  = lane & 15;
    const int half = quad & 1;
    const int lhalf = quad >> 1;

    // constants, L2-hot (8 KB shared by all waves)
    bf16x8 wf[8];
#pragma unroll
    for (int kb = 0; kb < 8; ++kb)
        wf[kb] = *(const bf16x8*)(wfrag + (kb * 64 + lane) * 8);
    const bf16x8 bq0 = *(const bf16x8*)(bond_bf + 0 * 16 + half * 8);
    const bf16x8 bq1 = *(const bf16x8*)(bond_bf + 1 * 16 + half * 8);
    const bf16x8 bq2 = *(const bf16x8*)(bond_bf + 2 * 16 + half * 8);
    const bf16x8 bq3 = *(const bf16x8*)(bond_bf + 3 * 16 + half * 8);
    const float bias_c = bias[col];

    Early earA, earB;
    Late  latA, latB;
    Gath  gA, gB;

    int tn = gw + GWAVES;      // tile whose gathers are issued next
    int tf = tn + GWAVES;      // tile whose streams are loaded next

    // prologue: fill the pipeline (every wave has >= 7 tiles, guards are
    // for safety only)
    load_early(earA, gw, col, lhalf, quad, n_col, p_row);
    load_late (latA, gw, col, lhalf, quad, n_val, e_val, be2, p_val);
    if (tn < NTILES) load_early(earB, tn, col, lhalf, quad, n_col, p_row);
    issue_gathers(gA, earA, nfeat_bf, fd, half, col);
    if (tn < NTILES) load_late(latB, tn, col, lhalf, quad, n_val, e_val, be2, p_val);

    for (;;) {
        STEP(A, B);
        STEP(B, A);
    }
tail_done: ;
}

// fallback only (workspace too small for fd table)
__global__ __launch_bounds__(256) void gate_kernel(
    const float* __restrict__ degs,  // [N]
    const float* __restrict__ W0,    // [1,32]
    const float* __restrict__ b0,    // [32]
    const float* __restrict__ W1,    // [32,16]
    const float* __restrict__ b1,    // [16]
    float* __restrict__ out)         // [N,16] in-place multiply
{
    int n = blockIdx.x * 256 + threadIdx.x;
    if (n >= NN) return;
    float dg = degs[n];
    float4 a0 = ((const float4*)b1)[0];
    float4 a1 = ((const float4*)b1)[1];
    float4 a2 = ((const float4*)b1)[2];
    float4 a3 = ((const float4*)b1)[3];
#pragma unroll
    for (int j = 0; j < 32; ++j) {
        float h = fmaxf(fmaf(dg, W0[j], b0[j]), 0.f);
        const float4* w1r = (const float4*)(W1 + j * 16);
        a0 = fma4(h, w1r[0], a0);
        a1 = fma4(h, w1r[1], a1);
        a2 = fma4(h, w1r[2], a2);
        a3 = fma4(h, w1r[3], a3);
    }
    float4* o = (float4*)(out + (size_t)n * DD);
    float4 v0 = o[0], v1 = o[1], v2 = o[2], v3 = o[3];
    v0.x *= a0.x; v0.y *= a0.y; v0.z *= a0.z; v0.w *= a0.w;
    v1.x *= a1.x; v1.y *= a1.y; v1.z *= a1.z; v1.w *= a1.w;
    v2.x *= a2.x; v2.y *= a2.y; v2.z *= a2.z; v2.w *= a2.w;
    v3.x *= a3.x; v3.y *= a3.y; v3.z *= a3.z; v3.w *= a3.w;
    o[0] = v0; o[1] = v1; o[2] = v2; o[3] = v3;
}

extern "C" void kernel_launch(void* const* d_in, const int* in_sizes, int n_in,
                              void* d_out, int out_size, void* d_ws, size_t ws_size,
                              hipStream_t stream) {
    const float* nfeat     = (const float*)d_in[0];
    const int*   efeat_idx = (const int*)d_in[1];
    // d_in[2] n_row = arange(M), unused
    const int*   n_col     = (const int*)d_in[3];
    const float* n_val     = (const float*)d_in[4];
    // d_in[5] e_row = arange(M), unused
    const int*   e_col     = (const int*)d_in[6];
    const float* e_val     = (const float*)d_in[7];
    const int*   p_row     = (const int*)d_in[8];
    // d_in[9] p_col = arange(P), unused
    const float* p_val     = (const float*)d_in[10];
    const float* degs      = (const float*)d_in[11];
    const float* weights   = (const float*)d_in[12];
    const float* bias      = (const float*)d_in[13];
    const float* W0        = (const float*)d_in[14];
    const float* b0        = (const float*)d_in[15];
    const float* W1        = (const float*)d_in[16];
    const float* b1        = (const float*)d_in[17];
    const float* bond_emb  = (const float*)d_in[18];

    float* out = (float*)d_out;

    // ws layout (16B-aligned blocks):
    //   wfrag 8KB | nfeat_bf 3.2MB | bond 128B | be2 1MB | fd 6.4MB (if it fits)
    char* wsb = (char*)d_ws;
    __bf16*        wfrag    = (__bf16*)wsb;                                // 8192 B
    __bf16*        nfeat_bf = (__bf16*)(wsb + 8192);                       // 3,200,000 B
    __bf16*        bond_bf  = (__bf16*)(wsb + 8192 + 3200000);             // 128 B
    unsigned char* be2      = (unsigned char*)(wsb + 8192 + 3200000 + 128);// 1,000,000 B
    const size_t base_need  = 8192 + 3200000 + 128 + 1000000;              // 4,208,320
    const bool   fuse_gate  = ws_size >= base_need + (size_t)NN * DD * 4;
    float*         fd       = fuse_gate ? (float*)(wsb + base_need) : nullptr;

    // grid must cover max(NN*DD, MM/4) = 1.6M threads
    init_kernel<<<(NN * DD + 255) / 256, 256, 0, stream>>>(
        weights, nfeat, bond_emb, e_col, efeat_idx,
        degs, W0, b0, W1, b1,
        wfrag, nfeat_bf, bond_bf, be2, fd, out);

    // 2048 persistent-ish waves, ~7.6 tiles each, depth-3 pipeline
    perm_kernel<<<PERM_BLOCKS, 256, 0, stream>>>(
        nfeat_bf, n_col, n_val, e_val, be2, p_row, p_val,
        wfrag, bias, bond_bf, fd, out);

    if (!fuse_gate)
        gate_kernel<<<(NN + 255) / 256, 256, 0, stream>>>(degs, W0, b0, W1, b1, out);
}

// Round 3
// 200.912 us; speedup vs baseline: 1.0633x; 1.0178x over previous
//
#include <hip/hip_runtime.h>

#define NP 250000   // P: permutations
#define NN 100000   // N: nodes
#define NE 400000   // E: edges
#define LL 16
#define DD 16
#define MM (NP * LL)        // 4,000,000
#define NTILES (NP / 16)    // 15625 exact
#define PERM_BLOCKS 1024
#define GWAVES (PERM_BLOCKS * 4)   // 4096 waves = 16/CU (VGPR=120 allows 16), ~3.8 tiles each

typedef __bf16 bf16x8 __attribute__((ext_vector_type(8)));
typedef float  f32x4  __attribute__((ext_vector_type(4)));
typedef int    i32x4  __attribute__((ext_vector_type(4)));

__device__ __forceinline__ float4 fma4(float a, float4 b, float4 c) {
    float4 r;
    r.x = fmaf(a, b.x, c.x);
    r.y = fmaf(a, b.y, c.y);
    r.z = fmaf(a, b.z, c.z);
    r.w = fmaf(a, b.w, c.w);
    return r;
}

// K-mapping for mfma_16x16x32_bf16, kb (0..7), lane (quad=lane>>4, c=lane&15):
//   d = 8*(quad&1) + j,  l = 8*(quad>>1) + kb
// wfrag[kb*512 + lane*8 + j] = weights[d][c][l]  (B-fragment order)
__global__ __launch_bounds__(256) void init_kernel(
    const float* __restrict__ w,          // [16,16,16] (d,c,l)
    const float* __restrict__ nfeat,      // [N,16]
    const float* __restrict__ bond_emb,   // [4,16]
    const int* __restrict__ e_col,        // [M]
    const int* __restrict__ efeat_idx,    // [E]
    const float* __restrict__ degs,       // [N]
    const float* __restrict__ W0,         // [1,32]
    const float* __restrict__ b0,         // [32]
    const float* __restrict__ W1,         // [32,16]
    const float* __restrict__ b1,         // [16]
    __bf16* __restrict__ wfrag,           // [8*64*8]
    __bf16* __restrict__ nfeat_bf,        // [N,16]
    __bf16* __restrict__ bond_bf,         // [4,16]
    unsigned char* __restrict__ be2,      // [M/4]
    float* __restrict__ fd,               // [N,16] or nullptr
    float* __restrict__ out)              // [N,16] -> zeroed
{
    int t = blockIdx.x * 256 + threadIdx.x;
    if (t < 4096) {
        int kb = t >> 9;
        int lane = (t >> 3) & 63;
        int j = t & 7;
        int quad = lane >> 4, c = lane & 15;
        int d = ((quad & 1) << 3) + j;
        int l = ((quad >> 1) << 3) + kb;
        wfrag[t] = (__bf16)w[d * 256 + c * 16 + l];
    }
    if (t < NN * DD) {
        nfeat_bf[t] = (__bf16)nfeat[t];
        out[t] = 0.f;
    }
    if (t < 64) bond_bf[t] = (__bf16)bond_emb[t];
    if (t < MM / 4) {
        int4 ec = *(const int4*)(e_col + t * 4);
        unsigned int c0 = (unsigned int)efeat_idx[ec.x] & 3u;
        unsigned int c1 = (unsigned int)efeat_idx[ec.y] & 3u;
        unsigned int c2 = (unsigned int)efeat_idx[ec.z] & 3u;
        unsigned int c3 = (unsigned int)efeat_idx[ec.w] & 3u;
        be2[t] = (unsigned char)(c0 | (c1 << 2) | (c2 << 4) | (c3 << 6));
    }
    if (fd != nullptr && t < NN) {
        float dg = degs[t];
        float4 a0 = ((const float4*)b1)[0];
        float4 a1 = ((const float4*)b1)[1];
        float4 a2 = ((const float4*)b1)[2];
        float4 a3 = ((const float4*)b1)[3];
#pragma unroll
        for (int j2 = 0; j2 < 32; ++j2) {
            float h = fmaxf(fmaf(dg, W0[j2], b0[j2]), 0.f);
            const float4* w1r = (const float4*)(W1 + j2 * 16);
            a0 = fma4(h, w1r[0], a0);
            a1 = fma4(h, w1r[1], a1);
            a2 = fma4(h, w1r[2], a2);
            a3 = fma4(h, w1r[3], a3);
        }
        float4* o = (float4*)(fd + (size_t)t * DD);
        o[0] = a0; o[1] = a1; o[2] = a2; o[3] = a3;
    }
}

// ---- pipelined perm kernel -------------------------------------------------
// Each wave owns ~3.8 tiles (grid-stride GWAVES). Depth-3 pipeline:
//   streams(t+2) in flight (HBM) / gathers(t+1) in flight (L2) / compute(t).
// Early group (n_col, p_row) is needed at gather-issue time; late group
// (n_val/e_val/p_val/be2) only at compute time. Named ping-pong structs keep
// all indexing compile-time constant (no scratch).

struct Early { i32x4 nca, ncb, pr; };
struct Late  { f32x4 nva, nvb, eva, evb, pv; unsigned int be16; };
struct Gath  { bf16x8 nfr[8]; float gv[4]; int prs[4]; };

__device__ __forceinline__ void load_early(Early& e, int tile, int col, int lhalf, int quad,
        const int* __restrict__ n_col, const int* __restrict__ p_row) {
    const int pbase = tile * 16;
    const int mbase = (pbase + col) * LL + lhalf * 8;
    e.nca = __builtin_nontemporal_load((const i32x4*)(n_col + mbase));
    e.ncb = __builtin_nontemporal_load((const i32x4*)(n_col + mbase + 4));
    e.pr  = __builtin_nontemporal_load((const i32x4*)(p_row + pbase + quad * 4));
}

__device__ __forceinline__ void load_late(Late& lt, int tile, int col, int lhalf, int quad,
        const float* __restrict__ n_val, const float* __restrict__ e_val,
        const unsigned char* __restrict__ be2, const float* __restrict__ p_val) {
    const int pbase = tile * 16;
    const int mbase = (pbase + col) * LL + lhalf * 8;
    lt.nva = __builtin_nontemporal_load((const f32x4*)(n_val + mbase));
    lt.nvb = __builtin_nontemporal_load((const f32x4*)(n_val + mbase + 4));
    lt.eva = __builtin_nontemporal_load((const f32x4*)(e_val + mbase));
    lt.evb = __builtin_nontemporal_load((const f32x4*)(e_val + mbase + 4));
    lt.pv  = __builtin_nontemporal_load((const f32x4*)(p_val + pbase + quad * 4));
    lt.be16 = (unsigned int)__builtin_nontemporal_load(
                  (const unsigned short*)(be2 + (mbase >> 2)));
}

__device__ __forceinline__ void issue_gathers(Gath& g, const Early& e,
        const __bf16* __restrict__ nfeat_bf, const float* __restrict__ fd,
        int half, int col) {
    int ncs[8] = {e.nca[0], e.nca[1], e.nca[2], e.nca[3],
                  e.ncb[0], e.ncb[1], e.ncb[2], e.ncb[3]};
#pragma unroll
    for (int kb = 0; kb < 8; ++kb)
        g.nfr[kb] = *(const bf16x8*)(nfeat_bf + (size_t)ncs[kb] * DD + half * 8);
#pragma unroll
    for (int r = 0; r < 4; ++r) {
        g.prs[r] = e.pr[r];
        g.gv[r] = fd ? fd[(size_t)e.pr[r] * DD + col] : 1.f;
    }
}

#define KSTEP(G, KB, NV, EV, J) do { \
    unsigned int b = (be >> (2 * (KB))) & 3u; \
    bf16x8 blo = (b & 1) ? bq1 : bq0; \
    bf16x8 bhi = (b & 1) ? bq3 : bq2; \
    bf16x8 bsel = (b & 2) ? bhi : blo; \
    float nv = (NV)[J], ev = (EV)[J]; \
    bf16x8 af; \
    _Pragma("unroll") \
    for (int j = 0; j < 8; ++j) \
        af[j] = (__bf16)fmaf(nv, (float)G.nfr[KB][j], ev * (float)bsel[j]); \
    acc = __builtin_amdgcn_mfma_f32_16x16x32_bf16(af, wf[KB], acc, 0, 0, 0); \
} while (0)

#define STEP(C, N) { \
    f32x4 acc = {0.f, 0.f, 0.f, 0.f}; \
    const unsigned int be = lat##C.be16; \
    KSTEP(g##C, 0, lat##C.nva, lat##C.eva, 0); \
    KSTEP(g##C, 1, lat##C.nva, lat##C.eva, 1); \
    KSTEP(g##C, 2, lat##C.nva, lat##C.eva, 2); \
    KSTEP(g##C, 3, lat##C.nva, lat##C.eva, 3); \
    if (tn < NTILES) issue_gathers(g##N, ear##N, nfeat_bf, fd, half, col); \
    if (tf < NTILES) load_early(ear##C, tf, col, lhalf, quad, n_col, p_row); \
    KSTEP(g##C, 4, lat##C.nvb, lat##C.evb, 0); \
    KSTEP(g##C, 5, lat##C.nvb, lat##C.evb, 1); \
    KSTEP(g##C, 6, lat##C.nvb, lat##C.evb, 2); \
    KSTEP(g##C, 7, lat##C.nvb, lat##C.evb, 3); \
    _Pragma("unroll") \
    for (int r = 0; r < 4; ++r) { \
        float v = fmaxf(acc[r] + bias_c, 0.f) * lat##C.pv[r] * g##C.gv[r]; \
        unsafeAtomicAdd(out + (size_t)g##C.prs[r] * DD + col, v); \
    } \
    if (tf < NTILES) load_late(lat##C, tf, col, lhalf, quad, n_val, e_val, be2, p_val); \
    if (tn >= NTILES) goto tail_done; \
    tn = tf; tf += GWAVES; \
}

__global__ __launch_bounds__(256) void perm_kernel(
    const __bf16* __restrict__ nfeat_bf,   // [N,16] bf16
    const int* __restrict__ n_col,         // [M]
    const float* __restrict__ n_val,       // [M]
    const float* __restrict__ e_val,       // [M]
    const unsigned char* __restrict__ be2, // [M/4] packed bond indices
    const int* __restrict__ p_row,         // [P]
    const float* __restrict__ p_val,       // [P]
    const __bf16* __restrict__ wfrag,      // [8*64*8]
    const float* __restrict__ bias,        // [16]
    const __bf16* __restrict__ bond_bf,    // [4,16] bf16
    const float* __restrict__ fd,          // [N,16] gate table, or nullptr
    float* __restrict__ out)               // [N,16] zero-initialized
{
    const int wid  = threadIdx.x >> 6;
    const int lane = threadIdx.x & 63;
    const int gw   = blockIdx.x * 4 + wid;   // 0..GWAVES-1
    const int quad = lane >> 4;
    const int col  = lane & 15;
    const int half = quad & 1;
    const int lhalf = quad >> 1;

    // constants, L2-hot (8 KB shared by all waves)
    bf16x8 wf[8];
#pragma unroll
    for (int kb = 0; kb < 8; ++kb)
        wf[kb] = *(const bf16x8*)(wfrag + (kb * 64 + lane) * 8);
    const bf16x8 bq0 = *(const bf16x8*)(bond_bf + 0 * 16 + half * 8);
    const bf16x8 bq1 = *(const bf16x8*)(bond_bf + 1 * 16 + half * 8);
    const bf16x8 bq2 = *(const bf16x8*)(bond_bf + 2 * 16 + half * 8);
    const bf16x8 bq3 = *(const bf16x8*)(bond_bf + 3 * 16 + half * 8);
    const float bias_c = bias[col];

    Early earA, earB;
    Late  latA, latB;
    Gath  gA, gB;

    int tn = gw + GWAVES;      // tile whose gathers are issued next
    int tf = tn + GWAVES;      // tile whose streams are loaded next

    // prologue: fill the pipeline (every wave has >= 3 tiles, guards cover
    // the rest)
    load_early(earA, gw, col, lhalf, quad, n_col, p_row);
    load_late (latA, gw, col, lhalf, quad, n_val, e_val, be2, p_val);
    if (tn < NTILES) load_early(earB, tn, col, lhalf, quad, n_col, p_row);
    issue_gathers(gA, earA, nfeat_bf, fd, half, col);
    if (tn < NTILES) load_late(latB, tn, col, lhalf, quad, n_val, e_val, be2, p_val);

    for (;;) {
        STEP(A, B);
        STEP(B, A);
    }
tail_done: ;
}

// fallback only (workspace too small for fd table)
__global__ __launch_bounds__(256) void gate_kernel(
    const float* __restrict__ degs,  // [N]
    const float* __restrict__ W0,    // [1,32]
    const float* __restrict__ b0,    // [32]
    const float* __restrict__ W1,    // [32,16]
    const float* __restrict__ b1,    // [16]
    float* __restrict__ out)         // [N,16] in-place multiply
{
    int n = blockIdx.x * 256 + threadIdx.x;
    if (n >= NN) return;
    float dg = degs[n];
    float4 a0 = ((const float4*)b1)[0];
    float4 a1 = ((const float4*)b1)[1];
    float4 a2 = ((const float4*)b1)[2];
    float4 a3 = ((const float4*)b1)[3];
#pragma unroll
    for (int j = 0; j < 32; ++j) {
        float h = fmaxf(fmaf(dg, W0[j], b0[j]), 0.f);
        const float4* w1r = (const float4*)(W1 + j * 16);
        a0 = fma4(h, w1r[0], a0);
        a1 = fma4(h, w1r[1], a1);
        a2 = fma4(h, w1r[2], a2);
        a3 = fma4(h, w1r[3], a3);
    }
    float4* o = (float4*)(out + (size_t)n * DD);
    float4 v0 = o[0], v1 = o[1], v2 = o[2], v3 = o[3];
    v0.x *= a0.x; v0.y *= a0.y; v0.z *= a0.z; v0.w *= a0.w;
    v1.x *= a1.x; v1.y *= a1.y; v1.z *= a1.z; v1.w *= a1.w;
    v2.x *= a2.x; v2.y *= a2.y; v2.z *= a2.z; v2.w *= a2.w;
    v3.x *= a3.x; v3.y *= a3.y; v3.z *= a3.z; v3.w *= a3.w;
    o[0] = v0; o[1] = v1; o[2] = v2; o[3] = v3;
}

extern "C" void kernel_launch(void* const* d_in, const int* in_sizes, int n_in,
                              void* d_out, int out_size, void* d_ws, size_t ws_size,
                              hipStream_t stream) {
    const float* nfeat     = (const float*)d_in[0];
    const int*   efeat_idx = (const int*)d_in[1];
    // d_in[2] n_row = arange(M), unused
    const int*   n_col     = (const int*)d_in[3];
    const float* n_val     = (const float*)d_in[4];
    // d_in[5] e_row = arange(M), unused
    const int*   e_col     = (const int*)d_in[6];
    const float* e_val     = (const float*)d_in[7];
    const int*   p_row     = (const int*)d_in[8];
    // d_in[9] p_col = arange(P), unused
    const float* p_val     = (const float*)d_in[10];
    const float* degs      = (const float*)d_in[11];
    const float* weights   = (const float*)d_in[12];
    const float* bias      = (const float*)d_in[13];
    const float* W0        = (const float*)d_in[14];
    const float* b0        = (const float*)d_in[15];
    const float* W1        = (const float*)d_in[16];
    const float* b1        = (const float*)d_in[17];
    const float* bond_emb  = (const float*)d_in[18];

    float* out = (float*)d_out;

    // ws layout (16B-aligned blocks):
    //   wfrag 8KB | nfeat_bf 3.2MB | bond 128B | be2 1MB | fd 6.4MB (if it fits)
    char* wsb = (char*)d_ws;
    __bf16*        wfrag    = (__bf16*)wsb;                                // 8192 B
    __bf16*        nfeat_bf = (__bf16*)(wsb + 8192);                       // 3,200,000 B
    __bf16*        bond_bf  = (__bf16*)(wsb + 8192 + 3200000);             // 128 B
    unsigned char* be2      = (unsigned char*)(wsb + 8192 + 3200000 + 128);// 1,000,000 B
    const size_t base_need  = 8192 + 3200000 + 128 + 1000000;              // 4,208,320
    const bool   fuse_gate  = ws_size >= base_need + (size_t)NN * DD * 4;
    float*         fd       = fuse_gate ? (float*)(wsb + base_need) : nullptr;

    // grid must cover max(NN*DD, MM/4) = 1.6M threads
    init_kernel<<<(NN * DD + 255) / 256, 256, 0, stream>>>(
        weights, nfeat, bond_emb, e_col, efeat_idx,
        degs, W0, b0, W1, b1,
        wfrag, nfeat_bf, bond_bf, be2, fd, out);

    // 4096 waves (= full VGPR-allowed residency of 16 waves/CU), ~3.8 tiles
    // each, depth-3 pipeline. ONLY change vs round 2: grid 512 -> 1024.
    perm_kernel<<<PERM_BLOCKS, 256, 0, stream>>>(
        nfeat_bf, n_col, n_val, e_val, be2, p_row, p_val,
        wfrag, bias, bond_bf, fd, out);

    if (!fuse_gate)
        gate_kernel<<<(NN + 255) / 256, 256, 0, stream>>>(degs, W0, b0, W1, b1, out);
}